// Round 4
// baseline (111.356 us; speedup 1.0000x reference)
//
#include <hip/hip_runtime.h>
#include <stdint.h>

typedef __attribute__((ext_vector_type(4))) int int4v;
typedef __attribute__((ext_vector_type(4))) float float4v;

#define NB 96
#define SS 1024
#define DD 64

// Pack byte0 of four int32s (each holding an int8 value) into one dword.
static __device__ __forceinline__ uint32_t pack4(uint32_t a, uint32_t b,
                                                 uint32_t c, uint32_t d) {
    uint32_t lo = __builtin_amdgcn_perm(b, a, 0x00000400u);  // [a0,b0,x,x]
    uint32_t hi = __builtin_amdgcn_perm(d, c, 0x00000400u);  // [c0,d0,x,x]
    return __builtin_amdgcn_perm(hi, lo, 0x05040100u);       // [a0,b0,c0,d0]
}

// out[b][s][t] = alpha * ( C - bz*rowsum(x) - az*colsum(y) + 64*az*bz )
// exact int32 via mfma_i32_16x16x64_i8; inputs arrive widened to int32.
// Swapped-operand MFMA: D^T = mfma(bF, aF) = (X.Y)^T, so each lane's 4 acc
// values are 4 consecutive output columns -> direct float4 store, no LDS
// epilogue, single barrier per block.
__global__ __launch_bounds__(256) void bmm_i8zp_kernel(
    const int* __restrict__ X,   // [96][1024][64] int32 (int8 values)
    const int* __restrict__ Y,   // [96][64][1024] int32
    const float* __restrict__ azp,
    const float* __restrict__ bzp,
    const float* __restrict__ alp,
    float* __restrict__ out)     // [96][1024][1024] fp32
{
    __shared__ uint32_t sa[128 * 16];   // packed i8 A tile, XOR-swizzled
    __shared__ uint32_t sb[128 * 16];   // packed+transposed i8 B tile

    const int tid = threadIdx.x;
    // XCD-aware swizzle: grid 6144 = 8 XCDs x 768; each XCD owns 12 batches
    const int bid = (blockIdx.x & 7) * 768 + (blockIdx.x >> 3);
    const int b   = bid >> 6;
    const int mt  = (bid >> 3) & 7;
    const int nt  = bid & 7;
    const int rowbase = mt * 128;
    const int colbase = nt * 128;

    const int* Xb = X + (size_t)b * (SS * DD);
    const int* Yb = Y + (size_t)b * (DD * SS);

    // ---- stage A panel (128 rows x 64 k), pack to i8, swizzled LDS ----
    {
        const int* Xa = Xb + (size_t)rowbase * DD;   // contiguous 32 KB panel
        #pragma unroll
        for (int i = 0; i < 8; ++i) {
            const int g = tid + 256 * i;             // 0..2047 int4v granules
            const int row = g >> 4, kw = g & 15;
            int4v w = *(const int4v*)(Xa + (size_t)g * 4);
            sa[row * 16 + (kw ^ (row & 15))] =
                pack4((uint32_t)w[0], (uint32_t)w[1], (uint32_t)w[2], (uint32_t)w[3]);
        }
    }
    // ---- stage + transpose B panel (64 k x 128 t) ----
    {
        const int tw = tid & 31;
        const int4v* srcBase = (const int4v*)(Yb + colbase) + tw;
        #pragma unroll
        for (int it = 0; it < 2; ++it) {
            const int kw = (tid >> 5) + 8 * it;      // 0..15
            const int4v* src = srcBase + (size_t)(4 * kw) * (SS / 4);
            int4v r0 = src[0];
            int4v r1 = src[SS / 4];
            int4v r2 = src[2 * (SS / 4)];
            int4v r3 = src[3 * (SS / 4)];
            const int t0 = 4 * tw;
            sb[(t0 + 0) * 16 + (kw ^ ((t0 + 0) & 15))] =
                pack4(r0[0], r1[0], r2[0], r3[0]);
            sb[(t0 + 1) * 16 + (kw ^ ((t0 + 1) & 15))] =
                pack4(r0[1], r1[1], r2[1], r3[1]);
            sb[(t0 + 2) * 16 + (kw ^ ((t0 + 2) & 15))] =
                pack4(r0[2], r1[2], r2[2], r3[2]);
            sb[(t0 + 3) * 16 + (kw ^ ((t0 + 3) & 15))] =
                pack4(r0[3], r1[3], r2[3], r3[3]);
        }
    }
    __syncthreads();

    const int wid  = tid >> 6;      // 4 waves, 2x2 over the 128x128 tile
    const int lane = tid & 63;
    const int wm = wid >> 1, wn = wid & 1;
    const int rr = lane & 15, qq = lane >> 4;

    int4v aF[4], bF[4];
    #pragma unroll
    for (int m = 0; m < 4; ++m) {
        const int lr = wm * 64 + m * 16 + rr;
        int4v v;
        #pragma unroll
        for (int c = 0; c < 4; ++c)
            v[c] = (int)sa[lr * 16 + ((qq * 4 + c) ^ (lr & 15))];
        aF[m] = v;
    }
    #pragma unroll
    for (int n = 0; n < 4; ++n) {
        const int t = wn * 64 + n * 16 + rr;
        int4v v;
        #pragma unroll
        for (int c = 0; c < 4; ++c)
            v[c] = (int)sb[t * 16 + ((qq * 4 + c) ^ (t & 15))];
        bF[n] = v;
    }

    const int4v ones = {0x01010101, 0x01010101, 0x01010101, 0x01010101};
    const int4v zero = {0, 0, 0, 0};

    // corrections, already in the swapped (D^T) layout:
    // cyD[n][j] = colsum_y[t = n*16 + qq*4 + j]   (same for all rr)
    // rxD[m][j] = rowsum_x[s = m*16 + rr]         (same for all j)
    int4v cyD[4], rxD[4];
    #pragma unroll
    for (int n = 0; n < 4; ++n)
        cyD[n] = __builtin_amdgcn_mfma_i32_16x16x64_i8(bF[n], ones, zero, 0, 0, 0);
    #pragma unroll
    for (int m = 0; m < 4; ++m)
        rxD[m] = __builtin_amdgcn_mfma_i32_16x16x64_i8(ones, aF[m], zero, 0, 0, 0);

    const float az = *azp, bz = *bzp, al = *alp;
    const float czk = az * bz * (float)DD;
    float* outb = out + (size_t)b * SS * SS;

    #pragma unroll
    for (int m = 0; m < 4; ++m) {
        const float corrR = czk - bz * (float)rxD[m][0];   // per-lane scalar
        const int rowg = rowbase + wm * 64 + m * 16 + rr;
        float* orow = outb + (size_t)rowg * SS + colbase + wn * 64 + qq * 4;
        #pragma unroll
        for (int n = 0; n < 4; ++n) {
            // D^T[t][s]: row = qq*4+j (t), col = rr (s)
            int4v acc = __builtin_amdgcn_mfma_i32_16x16x64_i8(bF[n], aF[m], zero, 0, 0, 0);
            float4v v;
            #pragma unroll
            for (int j = 0; j < 4; ++j)
                v[j] = ((float)acc[j] - az * (float)cyD[n][j] + corrR) * al;
            *(float4v*)(orow + n * 16) = v;
        }
    }
}

extern "C" void kernel_launch(void* const* d_in, const int* in_sizes, int n_in,
                              void* d_out, int out_size, void* d_ws, size_t ws_size,
                              hipStream_t stream)
{
    const int* X = (const int*)d_in[0];
    const int* Y = (const int*)d_in[1];
    const float* azp = (const float*)d_in[2];
    const float* bzp = (const float*)d_in[3];
    const float* alp = (const float*)d_in[4];
    float* out = (float*)d_out;

    dim3 grid(NB * 8 * 8);   // 96 batches x 8x8 tiles of 128x128
    dim3 block(256);
    hipLaunchKernelGGL(bmm_i8zp_kernel, grid, block, 0, stream, X, Y, azp, bzp, alp, out);
}

// Round 6
// 99.281 us; speedup vs baseline: 1.1216x; 1.1216x over previous
//
#include <hip/hip_runtime.h>
#include <stdint.h>

typedef __attribute__((ext_vector_type(4))) int int4v;
typedef __attribute__((ext_vector_type(4))) float float4v;

#define NB 96
#define SS 1024
#define DD 64
#define EPSTRIDE 68          // per-row f32 stride of per-wave epilogue buffer
#define EPW (16 * EPSTRIDE)  // 1088 f32 per wave

// Pack byte0 of four int32s (each holding an int8 value) into one dword.
static __device__ __forceinline__ uint32_t pack4(uint32_t a, uint32_t b,
                                                 uint32_t c, uint32_t d) {
    uint32_t lo = __builtin_amdgcn_perm(b, a, 0x00000400u);  // [a0,b0,x,x]
    uint32_t hi = __builtin_amdgcn_perm(d, c, 0x00000400u);  // [c0,d0,x,x]
    return __builtin_amdgcn_perm(hi, lo, 0x05040100u);       // [a0,b0,c0,d0]
}

// out[b][s][t] = alpha * ( C - bz*rowsum(x) - az*colsum(y) + 64*az*bz )
// exact int32 via mfma_i32_16x16x64_i8; inputs arrive widened to int32.
// Epilogue: per-wave private LDS transpose (no barriers), stores are
// 8 rows x 128B full aligned lines per instruction.
__global__ __launch_bounds__(256) void bmm_i8zp_kernel(
    const int* __restrict__ X,   // [96][1024][64] int32 (int8 values)
    const int* __restrict__ Y,   // [96][64][1024] int32
    const float* __restrict__ azp,
    const float* __restrict__ bzp,
    const float* __restrict__ alp,
    float* __restrict__ out)     // [96][1024][1024] fp32
{
    __shared__ union __align__(16) {
        struct { uint32_t a[128 * 16]; uint32_t b[128 * 16]; } s;  // 16 KB staging
        float e[4 * EPW];                                          // 17.4 KB epilogue
    } u;

    const int tid = threadIdx.x;
    // XCD-aware swizzle: grid 6144 = 8 XCDs x 768; each XCD owns 12 batches
    const int bid = (blockIdx.x & 7) * 768 + (blockIdx.x >> 3);
    const int b   = bid >> 6;
    const int mt  = (bid >> 3) & 7;
    const int nt  = bid & 7;
    const int rowbase = mt * 128;
    const int colbase = nt * 128;

    const int* Xb = X + (size_t)b * (SS * DD);
    const int* Yb = Y + (size_t)b * (DD * SS);

    const float az = *azp, bz = *bzp, al = *alp;
    const float czk = az * bz * (float)DD;

    // ---- stage A panel (128 rows x 64 k), pack to i8, swizzled LDS ----
    {
        const int* Xa = Xb + (size_t)rowbase * DD;   // contiguous 32 KB panel
        #pragma unroll
        for (int i = 0; i < 8; ++i) {
            const int g = tid + 256 * i;             // 0..2047 int4v granules
            const int row = g >> 4, kw = g & 15;
            int4v w = *(const int4v*)(Xa + (size_t)g * 4);
            u.s.a[row * 16 + (kw ^ (row & 15))] =
                pack4((uint32_t)w[0], (uint32_t)w[1], (uint32_t)w[2], (uint32_t)w[3]);
        }
    }
    // ---- stage + transpose B panel (64 k x 128 t) ----
    {
        const int tw = tid & 31;
        const int4v* srcBase = (const int4v*)(Yb + colbase) + tw;
        #pragma unroll
        for (int it = 0; it < 2; ++it) {
            const int kw = (tid >> 5) + 8 * it;      // 0..15
            const int4v* src = srcBase + (size_t)(4 * kw) * (SS / 4);
            int4v r0 = src[0];
            int4v r1 = src[SS / 4];
            int4v r2 = src[2 * (SS / 4)];
            int4v r3 = src[3 * (SS / 4)];
            const int t0 = 4 * tw;
            u.s.b[(t0 + 0) * 16 + (kw ^ ((t0 + 0) & 15))] =
                pack4(r0[0], r1[0], r2[0], r3[0]);
            u.s.b[(t0 + 1) * 16 + (kw ^ ((t0 + 1) & 15))] =
                pack4(r0[1], r1[1], r2[1], r3[1]);
            u.s.b[(t0 + 2) * 16 + (kw ^ ((t0 + 2) & 15))] =
                pack4(r0[2], r1[2], r2[2], r3[2]);
            u.s.b[(t0 + 3) * 16 + (kw ^ ((t0 + 3) & 15))] =
                pack4(r0[3], r1[3], r2[3], r3[3]);
        }
    }
    __syncthreads();

    const int wid  = tid >> 6;      // 4 waves, 2x2 over the 128x128 tile
    const int lane = tid & 63;
    const int wm = wid >> 1, wn = wid & 1;
    const int rr = lane & 15, qq = lane >> 4;

    int4v aF[4], bF[4];
    #pragma unroll
    for (int m = 0; m < 4; ++m) {
        const int lr = wm * 64 + m * 16 + rr;
        int4v v;
        #pragma unroll
        for (int c = 0; c < 4; ++c)
            v[c] = (int)u.s.a[lr * 16 + ((qq * 4 + c) ^ (lr & 15))];
        aF[m] = v;
    }
    #pragma unroll
    for (int n = 0; n < 4; ++n) {
        const int t = wn * 64 + n * 16 + rr;
        int4v v;
        #pragma unroll
        for (int c = 0; c < 4; ++c)
            v[c] = (int)u.s.b[t * 16 + ((qq * 4 + c) ^ (t & 15))];
        bF[n] = v;
    }
    __syncthreads();   // all frag reads done; LDS becomes per-wave epilogue bufs

    const int4v ones = {0x01010101, 0x01010101, 0x01010101, 0x01010101};
    const int4v zero = {0, 0, 0, 0};

    // colsum_y correction: cy[n] per-lane scalar (col t = n*16 + rr)
    float cyf[4];
    #pragma unroll
    for (int n = 0; n < 4; ++n) {
        int4v cy = __builtin_amdgcn_mfma_i32_16x16x64_i8(ones, bF[n], zero, 0, 0, 0);
        cyf[n] = az * (float)cy[0];
    }

    float* outb = out + (size_t)b * SS * SS;
    float* ew = &u.e[wid * EPW];

    #pragma unroll
    for (int m = 0; m < 4; ++m) {
        // rowsum_x correction: rx[j] = rowsum_x[row qq*4+j]
        int4v rx = __builtin_amdgcn_mfma_i32_16x16x64_i8(aF[m], ones, zero, 0, 0, 0);
        int4v acc[4];
        #pragma unroll
        for (int n = 0; n < 4; ++n)
            acc[n] = __builtin_amdgcn_mfma_i32_16x16x64_i8(aF[m], bF[n], zero, 0, 0, 0);

        // scatter into private 16x64 buffer (stride 68 -> 2-way banks, free)
        #pragma unroll
        for (int j = 0; j < 4; ++j) {
            const float corr = czk - bz * (float)rx[j];
            #pragma unroll
            for (int n = 0; n < 4; ++n)
                ew[(qq * 4 + j) * EPSTRIDE + n * 16 + rr] =
                    ((float)acc[n][j] - cyf[n] + corr) * al;
        }
        // read back + store: 8 rows x 128B full aligned lines per instruction
        const int rbase = rowbase + wm * 64 + m * 16;
        const int cbase = colbase + wn * 64;
        #pragma unroll
        for (int i = 0; i < 4; ++i) {
            const int row = (lane >> 3) + 8 * (i >> 1);
            const int col = (lane & 7) * 4 + 32 * (i & 1);
            float4v v = *(const float4v*)&ew[row * EPSTRIDE + col];
            *(float4v*)(outb + (size_t)(rbase + row) * SS + cbase + col) = v;
        }
    }
}

extern "C" void kernel_launch(void* const* d_in, const int* in_sizes, int n_in,
                              void* d_out, int out_size, void* d_ws, size_t ws_size,
                              hipStream_t stream)
{
    const int* X = (const int*)d_in[0];
    const int* Y = (const int*)d_in[1];
    const float* azp = (const float*)d_in[2];
    const float* bzp = (const float*)d_in[3];
    const float* alp = (const float*)d_in[4];
    float* out = (float*)d_out;

    dim3 grid(NB * 8 * 8);   // 96 batches x 8x8 tiles of 128x128
    dim3 block(256);
    hipLaunchKernelGGL(bmm_i8zp_kernel, grid, block, 0, stream, X, Y, azp, bzp, alp, out);
}

// Round 7
// 87.144 us; speedup vs baseline: 1.2778x; 1.1393x over previous
//
#include <hip/hip_runtime.h>
#include <stdint.h>

typedef __attribute__((ext_vector_type(4))) int int4v;
typedef __attribute__((ext_vector_type(4))) float float4v;

#define NB 96
#define SS 1024
#define DD 64
#define EPSTRIDE 68          // per-row f32 stride of per-wave epilogue buffer
#define EPW (16 * EPSTRIDE)  // 1088 f32 per wave
#define TILE_U32 2048        // 8 KB packed image per 128x64 tile
#define NTILES (NB * 8)      // 768 tiles per operand

// Pack byte0 of four int32s (each holding an int8 value) into one dword.
static __device__ __forceinline__ uint32_t pack4(uint32_t a, uint32_t b,
                                                 uint32_t c, uint32_t d) {
    uint32_t lo = __builtin_amdgcn_perm(b, a, 0x00000400u);  // [a0,b0,x,x]
    uint32_t hi = __builtin_amdgcn_perm(d, c, 0x00000400u);  // [c0,d0,x,x]
    return __builtin_amdgcn_perm(hi, lo, 0x05040100u);       // [a0,b0,c0,d0]
}

// Pre-pack int32-widened inputs into the exact swizzled LDS tile images.
// Xp[tile=b*8+mt][row*16 + kw^(row&15)] = packed X[b][mt*128+row][4kw..4kw+3]
// Yp[tile=b*8+nt][t*16  + kw^(t&15) ]  = packed Y[b][4kw..4kw+3][nt*128+t]
__global__ __launch_bounds__(256) void pack_kernel(
    const int* __restrict__ X, const int* __restrict__ Y,
    uint32_t* __restrict__ Xp, uint32_t* __restrict__ Yp)
{
    const int tid = threadIdx.x;
    const int blk = blockIdx.x;
    if (blk < NTILES) {
        const int* Xa = X + (size_t)blk * (128 * DD);
        uint32_t* dst = Xp + (size_t)blk * TILE_U32;
        #pragma unroll
        for (int i = 0; i < 8; ++i) {
            const int g = tid + 256 * i;
            const int row = g >> 4, kw = g & 15;
            int4v w = *(const int4v*)(Xa + (size_t)g * 4);
            dst[row * 16 + (kw ^ (row & 15))] =
                pack4((uint32_t)w[0], (uint32_t)w[1], (uint32_t)w[2], (uint32_t)w[3]);
        }
    } else {
        __shared__ uint32_t sb[TILE_U32];
        const int t2 = blk - NTILES;
        const int b = t2 >> 3, nt = t2 & 7;
        const int* Yb = Y + (size_t)b * (DD * SS) + nt * 128;
        const int tw = tid & 31;
        const int4v* srcBase = (const int4v*)Yb + tw;
        #pragma unroll
        for (int it = 0; it < 2; ++it) {
            const int kw = (tid >> 5) + 8 * it;
            const int4v* src = srcBase + (size_t)(4 * kw) * (SS / 4);
            int4v r0 = src[0];
            int4v r1 = src[SS / 4];
            int4v r2 = src[2 * (SS / 4)];
            int4v r3 = src[3 * (SS / 4)];
            const int t0 = 4 * tw;
            sb[(t0 + 0) * 16 + (kw ^ ((t0 + 0) & 15))] =
                pack4(r0[0], r1[0], r2[0], r3[0]);
            sb[(t0 + 1) * 16 + (kw ^ ((t0 + 1) & 15))] =
                pack4(r0[1], r1[1], r2[1], r3[1]);
            sb[(t0 + 2) * 16 + (kw ^ ((t0 + 2) & 15))] =
                pack4(r0[2], r1[2], r2[2], r3[2]);
            sb[(t0 + 3) * 16 + (kw ^ ((t0 + 3) & 15))] =
                pack4(r0[3], r1[3], r2[3], r3[3]);
        }
        __syncthreads();
        uint32_t* dst = Yp + (size_t)t2 * TILE_U32;
        ((int4v*)dst)[tid]       = ((const int4v*)sb)[tid];
        ((int4v*)dst)[tid + 256] = ((const int4v*)sb)[tid + 256];
    }
}

// out[b][s][t] = alpha * ( C - bz*rowsum(x) - az*colsum(y) + 64*az*bz )
// exact int32 via mfma_i32_16x16x64_i8.
__global__ __launch_bounds__(256) void bmm_i8zp_kernel(
    const int* __restrict__ X,   // [96][1024][64] int32 (int8 values)
    const int* __restrict__ Y,   // [96][64][1024] int32
    const uint32_t* __restrict__ Xp,
    const uint32_t* __restrict__ Yp,
    const float* __restrict__ azp,
    const float* __restrict__ bzp,
    const float* __restrict__ alp,
    float* __restrict__ out,     // [96][1024][1024] fp32
    int packed)
{
    __shared__ union __align__(16) {
        struct { uint32_t a[TILE_U32]; uint32_t b[TILE_U32]; } s;  // 16 KB staging
        float e[4 * EPW];                                          // 17.4 KB epilogue
    } u;

    const int tid = threadIdx.x;
    // XCD-aware swizzle: grid 6144 = 8 XCDs x 768; each XCD owns 12 batches
    const int bid = (blockIdx.x & 7) * 768 + (blockIdx.x >> 3);
    const int b   = bid >> 6;
    const int mt  = (bid >> 3) & 7;
    const int nt  = bid & 7;
    const int rowbase = mt * 128;
    const int colbase = nt * 128;

    const float az = *azp, bz = *bzp, al = *alp;
    const float czk = az * bz * (float)DD;

    if (packed) {
        // linear copy of pre-swizzled 8 KB images into LDS
        const int4v* Ximg = (const int4v*)(Xp + ((size_t)b * 8 + mt) * TILE_U32);
        const int4v* Yimg = (const int4v*)(Yp + ((size_t)b * 8 + nt) * TILE_U32);
        int4v a0 = Ximg[tid], a1 = Ximg[tid + 256];
        int4v b0 = Yimg[tid], b1 = Yimg[tid + 256];
        ((int4v*)u.s.a)[tid]       = a0;
        ((int4v*)u.s.a)[tid + 256] = a1;
        ((int4v*)u.s.b)[tid]       = b0;
        ((int4v*)u.s.b)[tid + 256] = b1;
    } else {
        const int* Xb = X + (size_t)b * (SS * DD);
        const int* Yb = Y + (size_t)b * (DD * SS);
        const int* Xa = Xb + (size_t)rowbase * DD;
        #pragma unroll
        for (int i = 0; i < 8; ++i) {
            const int g = tid + 256 * i;
            const int row = g >> 4, kw = g & 15;
            int4v w = *(const int4v*)(Xa + (size_t)g * 4);
            u.s.a[row * 16 + (kw ^ (row & 15))] =
                pack4((uint32_t)w[0], (uint32_t)w[1], (uint32_t)w[2], (uint32_t)w[3]);
        }
        const int tw = tid & 31;
        const int4v* srcBase = (const int4v*)(Yb + colbase) + tw;
        #pragma unroll
        for (int it = 0; it < 2; ++it) {
            const int kw = (tid >> 5) + 8 * it;
            const int4v* src = srcBase + (size_t)(4 * kw) * (SS / 4);
            int4v r0 = src[0];
            int4v r1 = src[SS / 4];
            int4v r2 = src[2 * (SS / 4)];
            int4v r3 = src[3 * (SS / 4)];
            const int t0 = 4 * tw;
            u.s.b[(t0 + 0) * 16 + (kw ^ ((t0 + 0) & 15))] =
                pack4(r0[0], r1[0], r2[0], r3[0]);
            u.s.b[(t0 + 1) * 16 + (kw ^ ((t0 + 1) & 15))] =
                pack4(r0[1], r1[1], r2[1], r3[1]);
            u.s.b[(t0 + 2) * 16 + (kw ^ ((t0 + 2) & 15))] =
                pack4(r0[2], r1[2], r2[2], r3[2]);
            u.s.b[(t0 + 3) * 16 + (kw ^ ((t0 + 3) & 15))] =
                pack4(r0[3], r1[3], r2[3], r3[3]);
        }
    }
    __syncthreads();

    const int wid  = tid >> 6;      // 4 waves, 2x2 over the 128x128 tile
    const int lane = tid & 63;
    const int wm = wid >> 1, wn = wid & 1;
    const int rr = lane & 15, qq = lane >> 4;

    int4v aF[4], bF[4];
    #pragma unroll
    for (int m = 0; m < 4; ++m) {
        const int lr = wm * 64 + m * 16 + rr;
        int4v v;
        #pragma unroll
        for (int c = 0; c < 4; ++c)
            v[c] = (int)u.s.a[lr * 16 + ((qq * 4 + c) ^ (lr & 15))];
        aF[m] = v;
    }
    #pragma unroll
    for (int n = 0; n < 4; ++n) {
        const int t = wn * 64 + n * 16 + rr;
        int4v v;
        #pragma unroll
        for (int c = 0; c < 4; ++c)
            v[c] = (int)u.s.b[t * 16 + ((qq * 4 + c) ^ (t & 15))];
        bF[n] = v;
    }
    __syncthreads();   // all frag reads done; LDS becomes per-wave epilogue bufs

    const int4v ones = {0x01010101, 0x01010101, 0x01010101, 0x01010101};
    const int4v zero = {0, 0, 0, 0};

    float cyf[4];
    #pragma unroll
    for (int n = 0; n < 4; ++n) {
        int4v cy = __builtin_amdgcn_mfma_i32_16x16x64_i8(ones, bF[n], zero, 0, 0, 0);
        cyf[n] = az * (float)cy[0];
    }

    float* outb = out + (size_t)b * SS * SS;
    float* ew = &u.e[wid * EPW];

    #pragma unroll
    for (int m = 0; m < 4; ++m) {
        int4v rx = __builtin_amdgcn_mfma_i32_16x16x64_i8(aF[m], ones, zero, 0, 0, 0);
        int4v acc[4];
        #pragma unroll
        for (int n = 0; n < 4; ++n)
            acc[n] = __builtin_amdgcn_mfma_i32_16x16x64_i8(aF[m], bF[n], zero, 0, 0, 0);

        #pragma unroll
        for (int j = 0; j < 4; ++j) {
            const float corr = czk - bz * (float)rx[j];
            #pragma unroll
            for (int n = 0; n < 4; ++n)
                ew[(qq * 4 + j) * EPSTRIDE + n * 16 + rr] =
                    ((float)acc[n][j] - cyf[n] + corr) * al;
        }
        const int rbase = rowbase + wm * 64 + m * 16;
        const int cbase = colbase + wn * 64;
        #pragma unroll
        for (int i = 0; i < 4; ++i) {
            const int row = (lane >> 3) + 8 * (i >> 1);
            const int col = (lane & 7) * 4 + 32 * (i & 1);
            float4v v = *(const float4v*)&ew[row * EPSTRIDE + col];
            __builtin_nontemporal_store(
                v, (float4v*)(outb + (size_t)(rbase + row) * SS + cbase + col));
        }
    }
}

extern "C" void kernel_launch(void* const* d_in, const int* in_sizes, int n_in,
                              void* d_out, int out_size, void* d_ws, size_t ws_size,
                              hipStream_t stream)
{
    const int* X = (const int*)d_in[0];
    const int* Y = (const int*)d_in[1];
    const float* azp = (const float*)d_in[2];
    const float* bzp = (const float*)d_in[3];
    const float* alp = (const float*)d_in[4];
    float* out = (float*)d_out;

    const size_t need = 2ull * NTILES * TILE_U32 * sizeof(uint32_t);  // 12.6 MB
    const int packed = (ws_size >= need) ? 1 : 0;
    uint32_t* Xp = (uint32_t*)d_ws;
    uint32_t* Yp = Xp + (size_t)NTILES * TILE_U32;

    if (packed) {
        hipLaunchKernelGGL(pack_kernel, dim3(2 * NTILES), dim3(256), 0, stream,
                           X, Y, Xp, Yp);
    }
    hipLaunchKernelGGL(bmm_i8zp_kernel, dim3(NB * 8 * 8), dim3(256), 0, stream,
                       X, Y, Xp, Yp, azp, bzp, alp, out, packed);
}